// Round 1
// baseline (130.423 us; speedup 1.0000x reference)
//
#include <hip/hip_runtime.h>
#include <stdint.h>
#include <stddef.h>

#define BDIM 4
#define QUE  128
#define VAL  128
#define DD   512
#define BQ   (BDIM*QUE)
#define BK   64
// gemm LDS: 8 slots of 8 f16 (16B) per row; true kseg c stored at slot (c + (r&7)) & 7

typedef float    f32x4 __attribute__((ext_vector_type(4)));
typedef float    f32x2 __attribute__((ext_vector_type(2)));
typedef _Float16 f16x8 __attribute__((ext_vector_type(8)));
typedef _Float16 f16x4 __attribute__((ext_vector_type(4)));
typedef _Float16 f16x2 __attribute__((ext_vector_type(2)));

typedef const __attribute__((address_space(1))) void* gas_ptr;
typedef __attribute__((address_space(3))) void*       las_ptr;

__device__ __forceinline__ void async_copy16(const void* g, void* l) {
    __builtin_amdgcn_global_load_lds((gas_ptr)g, (las_ptr)l, 16, 0, 0);
}

// ---------------- prep: fp16 transposes  W1->W1T[e][d], Wse->WseT[d][e],
//                  vs->vsT[b][d][v]; flat fp16 casts qs1->qH, ks->ksH ----------
__global__ __launch_bounds__(256) void prep_kernel(const float* __restrict__ W1,
                                                   _Float16* __restrict__ W1T,
                                                   const float* __restrict__ Wse,
                                                   _Float16* __restrict__ WseT,
                                                   const float* __restrict__ vs,
                                                   _Float16* __restrict__ vsT,
                                                   const float* __restrict__ qs1,
                                                   _Float16* __restrict__ qH,
                                                   const float* __restrict__ ks,
                                                   _Float16* __restrict__ ksH) {
    const int gx = blockIdx.x, gy = blockIdx.y;
    if (gy >= 36) {
        // flat cast: gy==36 -> qs1->qH, gy==37 -> ks->ksH (262144 f32 each)
        const float* src = (gy == 36) ? qs1 : ks;
        _Float16*    dst = (gy == 36) ? qH  : ksH;
        size_t base = (size_t)gx * 16384 + threadIdx.x * 4;
        #pragma unroll 4
        for (int i = 0; i < 16; ++i) {
            f32x4 w = *(const f32x4*)(src + base + (size_t)i * 1024);
            f16x4 h;
            h[0] = (_Float16)w[0]; h[1] = (_Float16)w[1];
            h[2] = (_Float16)w[2]; h[3] = (_Float16)w[3];
            *(f16x4*)(dst + base + (size_t)i * 1024) = h;
        }
        return;
    }
    __shared__ float tile[32][33];
    const int tx = threadIdx.x & 31;
    const int ty = threadIdx.x >> 5;      // 0..7
    if (gy < 32) {
        const float* src = (gy < 16) ? W1  : Wse;
        _Float16*    dst = (gy < 16) ? W1T : WseT;
        int a0 = gx * 32;                 // source-row tile
        int b0 = (gy & 15) * 32;          // source-col tile
        #pragma unroll
        for (int r = 0; r < 4; ++r)
            tile[ty + r*8][tx] = src[(size_t)(a0 + ty + r*8) * DD + b0 + tx];
        __syncthreads();
        #pragma unroll
        for (int r = 0; r < 4; ++r) {
            int el = ty + r*8;
            dst[(size_t)(b0 + el) * DD + a0 + tx] = (_Float16)tile[tx][el];
        }
    } else {
        // vs[b][v][d] -> vsT[b][d][v], b = gy-32, d-tile = gx
        int bb = gy - 32;
        const float* src = vs  + (size_t)bb * VAL * DD;
        _Float16*    dst = vsT + (size_t)bb * DD * VAL;
        int b0 = gx * 32;                 // d tile
        for (int vt = 0; vt < 4; ++vt) {
            int a0 = vt * 32;             // v tile
            __syncthreads();
            #pragma unroll
            for (int r = 0; r < 4; ++r)
                tile[ty + r*8][tx] = src[(size_t)(a0 + ty + r*8) * DD + b0 + tx];
            __syncthreads();
            #pragma unroll
            for (int r = 0; r < 4; ++r) {
                int el = ty + r*8;
                dst[(size_t)(b0 + el) * VAL + a0 + tx] = (_Float16)tile[tx][el];
            }
        }
    }
}

// ---------------- fused GEMM: h=relu((q*k)@W1+b1); emit s-partials + masked colsums
// grid (BQ, 4); block 256 = 4 waves as 2m x 2n of 64x64. Tile 128 rows x 128 e-cols.
// Zero-exposed-latency schedule:
//   top of step: ds_read ALL B frags -> regs; lgkmcnt(0)+s_barrier (Bh now free)
//   then: stage A(i+1) -> Ah[p^1] (regs prefetched last step), issue A(i+2) loads,
//         issue B(i+1) asyncs -> Bh (flight window = whole MFMA phase)
//   MFMA phase reads fa from Ah[p] (double-buffered); __syncthreads drains all.
__global__ __launch_bounds__(256, 3) void gemm_h_kernel(
    const _Float16* __restrict__ qH,    // [BQ][DD] fp16
    const _Float16* __restrict__ ksH,   // [B][VAL][DD] fp16
    const int*   __restrict__ sgmask,
    const _Float16* __restrict__ W1T,   // [e][d] fp16
    const float* __restrict__ b1,
    const float* __restrict__ W2,
    float* __restrict__ s_part,         // [BQ][4][VAL]
    float* __restrict__ meansum)        // [BQ][DD]
{
    __shared__ _Float16 Ah[2][128 * BK];  // x tile   [v][k]  16 KB x2 (dbuf)
    __shared__ _Float16 Bh[128 * BK];     // W1T tile [e][k]  16 KB (single)
    __shared__ float sred[2][VAL];
    __shared__ float msumLDS[2][128];

    const int tid  = threadIdx.x;
    const int bq   = blockIdx.x;
    const int gy   = blockIdx.y;          // e-quarter: cols [gy*128, gy*128+128)
    const int b    = bq >> 7;
    const int lane = tid & 63;
    const int wid  = tid >> 6;            // 0..3
    const int wm   = wid >> 1;            // 0..1 (rows wm*64)
    const int wn   = wid & 1;             // 0..1 (cols wn*64)
    const int quad = lane >> 4;
    const int lr   = lane & 15;

    f32x4 acc[4][4];
    #pragma unroll
    for (int i = 0; i < 4; ++i)
        #pragma unroll
        for (int j = 0; j < 4; ++j) acc[i][j] = (f32x4){0.f, 0.f, 0.f, 0.f};

    // ---- A staging: 4 chunks/thread (chunk = j*256+tid); row = chunk>>3, slot = chunk&7
    //      rows tid>>3 + 32j share the same true kseg (32 ≡ 0 mod 8)
    const int ar0 = tid >> 3;             // base row 0..31
    const int slt = tid & 7;
    const int ca0 = (slt - (ar0 & 7)) & 7;   // true kseg
    const _Float16* ksrow0 = ksH + ((size_t)b * VAL + ar0) * DD + ca0 * 8;
    const _Float16* qrow_g = qH  + (size_t)bq * DD + ca0 * 8;   // L1-broadcast row
    const int aoff0 = tid * 8;            // f16 units within one Ah buffer

    // ---- B staging: 4 asyncs/thread; async j covers chunks j*256 + tid ----
    const int brow0 = tid >> 3;           // 0..31
    const int bc0   = ((tid & 7) - (brow0 & 7)) & 7;
    const _Float16* gB0 = W1T + (size_t)(gy * 128 + brow0) * DD + bc0 * 8;

    // ---- fragment offsets (f16 units); sub-step 1 = offset XOR 32 (slot+4 mod 8) ----
    int faoff[4], fboff[4];
    #pragma unroll
    for (int mt = 0; mt < 4; ++mt) {
        int row = wm * 64 + mt * 16 + lr;
        faoff[mt] = row * BK + (((quad + row) & 7) << 3);
    }
    #pragma unroll
    for (int nt = 0; nt < 4; ++nt) {
        int row = wn * 64 + nt * 16 + lr;
        fboff[nt] = row * BK + (((quad + row) & 7) << 3);
    }

    // ---- prologue: B(0) asyncs, A(0) stage, A(1) reg prefetch ----
    #pragma unroll
    for (int j = 0; j < 4; ++j)
        async_copy16(gB0 + (size_t)j * 32 * DD, &Bh[(j * 256 + wid * 64) * 8]);
    f16x8 kv[4], qv;
    #pragma unroll
    for (int j = 0; j < 4; ++j)
        kv[j] = *(const f16x8*)(ksrow0 + (size_t)j * 32 * DD);
    qv = *(const f16x8*)(qrow_g);
    #pragma unroll
    for (int j = 0; j < 4; ++j)
        *(f16x8*)&Ah[0][aoff0 + j * 2048] = kv[j] * qv;
    #pragma unroll
    for (int j = 0; j < 4; ++j)
        kv[j] = *(const f16x8*)(ksrow0 + (size_t)j * 32 * DD + BK);
    qv = *(const f16x8*)(qrow_g + BK);
    __syncthreads();                      // B(0), A(0) resident

    int p = 0;
    for (int i = 0; i < 8; ++i) {
        // ---- pull ALL B frags (both K=32 subs) into regs; then Bh is free
        f16x8 fbr[2][4];
        #pragma unroll
        for (int s = 0; s < 2; ++s) {
            const int sx = s << 5;
            #pragma unroll
            for (int nt = 0; nt < 4; ++nt)
                fbr[s][nt] = *(const f16x8*)&Bh[fboff[nt] ^ sx];
        }
        asm volatile("s_waitcnt lgkmcnt(0)" ::: "memory");
        __builtin_amdgcn_s_barrier();     // all waves' B reads done -> Bh reusable

        if (i < 7) {
            const int kk = (i + 1) * BK;
            // stage A(i+1) from regs (loaded last step; resident since last barrier)
            #pragma unroll
            for (int j = 0; j < 4; ++j)
                *(f16x8*)&Ah[p ^ 1][aoff0 + j * 2048] = kv[j] * qv;
            if (i < 6) {
                #pragma unroll
                for (int j = 0; j < 4; ++j)
                    kv[j] = *(const f16x8*)(ksrow0 + (size_t)j * 32 * DD + kk + BK);
                qv = *(const f16x8*)(qrow_g + kk + BK);
            }
            // B(i+1) asyncs: in flight across the whole MFMA phase
            #pragma unroll
            for (int j = 0; j < 4; ++j)
                async_copy16(gB0 + (size_t)j * 32 * DD + kk,
                             &Bh[(j * 256 + wid * 64) * 8]);
        }

        // ---- MFMA: fa streamed from Ah[p] (safe: staging went to Ah[p^1])
        const _Float16* Ab = &Ah[p][0];
        #pragma unroll
        for (int s = 0; s < 2; ++s) {
            const int sx = s << 5;
            f16x8 fa[4];
            #pragma unroll
            for (int mt = 0; mt < 4; ++mt)
                fa[mt] = *(const f16x8*)&Ab[faoff[mt] ^ sx];
            #pragma unroll
            for (int nt = 0; nt < 4; ++nt)
                #pragma unroll
                for (int mt = 0; mt < 4; ++mt)
                    acc[mt][nt] = __builtin_amdgcn_mfma_f32_16x16x32_f16(
                        fa[mt], fbr[s][nt], acc[mt][nt], 0, 0, 0);
        }
        __syncthreads();                  // drains B(i+1) asyncs + A loads (gap = MFMA)
        p ^= 1;
    }

    // ---- fused epilogue: C/D layout col=lr (e), row=quad*4+reg (v)
    float b1v[4], w2v[4];
    #pragma unroll
    for (int nt = 0; nt < 4; ++nt) {
        int col = gy*128 + wn*64 + nt*16 + lr;
        b1v[nt] = b1[col];
        w2v[nt] = W2[col];
    }
    float msum[4] = {0.f, 0.f, 0.f, 0.f};
    #pragma unroll
    for (int mt = 0; mt < 4; ++mt) {
        #pragma unroll
        for (int reg = 0; reg < 4; ++reg) {
            int v = wm*64 + mt*16 + quad*4 + reg;
            int masked = sgmask[b * VAL + v];
            float sacc = 0.f;
            #pragma unroll
            for (int nt = 0; nt < 4; ++nt) {
                float h = acc[mt][nt][reg] + b1v[nt];
                h = fmaxf(h, 0.f);
                sacc += h * w2v[nt];
                if (!masked) msum[nt] += h;
            }
            sacc += __shfl_xor(sacc, 1);
            sacc += __shfl_xor(sacc, 2);
            sacc += __shfl_xor(sacc, 4);
            sacc += __shfl_xor(sacc, 8);
            if (lr == 0) sred[wn][v] = sacc;
        }
    }
    #pragma unroll
    for (int nt = 0; nt < 4; ++nt) {
        float m = msum[nt];
        m += __shfl_xor(m, 16);
        m += __shfl_xor(m, 32);
        if (lane < 16) msumLDS[wm][wn*64 + nt*16 + lr] = m;
    }
    __syncthreads();
    if (tid < 128) {
        s_part[((size_t)bq * 4 + gy) * VAL + tid] = sred[0][tid] + sred[1][tid];
    } else {
        int c = tid - 128;
        meansum[(size_t)bq * DD + gy*128 + c] = msumLDS[0][c] + msumLDS[1][c];
    }
}

// ---------------- final (fuses mid): softmax+mean in-block, then two LDS-staged
// mini-GEMMs. grid (16 q-tiles of 32, 16 d-tiles of 32), 256 thr = 4 waves (2m x 2n).
#define MPAD 514   // meanLDS row stride (f16): 257 dwords === 1 mod 32 -> conflict-free
#define WPAD 130   // wLDS/BLDS row stride: 65 dwords === 1 mod 32
__global__ __launch_bounds__(256) void final_kernel(
    const float* __restrict__ s_part,     // [BQ][4][VAL]
    const float* __restrict__ msum,       // [BQ][DD]
    const int*   __restrict__ sgmask,
    const _Float16* __restrict__ WseT,    // [d][e] fp16
    const _Float16* __restrict__ vsT,     // [b][d][v] fp16
    const float* __restrict__ bse,
    const float* __restrict__ b2,
    float* __restrict__ out)              // [BQ][DD]
{
    __shared__ _Float16 meanLDS[32 * MPAD];   // 32.9 KB  A of gate GEMM (all 512 e)
    __shared__ _Float16 wLDS[32 * WPAD];      //  8.3 KB  A of out GEMM
    __shared__ _Float16 BLDS[32 * WPAD];      //  8.3 KB  B chunk (WseT then vsT)

    const int tid  = threadIdx.x;
    const int q0   = blockIdx.x * 32;
    const int d0   = blockIdx.y * 32;
    const int b    = q0 >> 7;                 // whole q-tile within one batch
    const int lane = tid & 63;
    const int wid  = tid >> 6;                // 0..3
    const int wm   = wid >> 1, wn = wid & 1;  // 2m x 2n of 16x16
    const int quad = lane >> 4;
    const int lr   = lane & 15;
    const int r    = tid >> 3;                // 0..31 (row for staging/softmax)
    const int sl   = tid & 7;                 // 0..7  (segment)

    // ---- phase A: softmax over v (8 lanes/row) + mean (fold 1/denom) ----
    const float b2v = b2[0];
    const int   bq  = q0 + r;
    const float* sp = s_part + (size_t)bq * 4 * VAL;
    float vals[16];
    int   msk[16];
    float smax = -3.4e38f;
    #pragma unroll
    for (int i4 = 0; i4 < 4; ++i4) {
        f32x4 s0 = *(const f32x4*)(sp +           sl*16 + i4*4);
        f32x4 s1 = *(const f32x4*)(sp + VAL     + sl*16 + i4*4);
        f32x4 s2 = *(const f32x4*)(sp + 2*VAL   + sl*16 + i4*4);
        f32x4 s3 = *(const f32x4*)(sp + 3*VAL   + sl*16 + i4*4);
        #pragma unroll
        for (int j = 0; j < 4; ++j) {
            int idx = i4*4 + j;
            int v   = sl*16 + idx;
            float s = fmaxf(s0[j] + s1[j] + s2[j] + s3[j] + b2v, 0.f);
            int m   = sgmask[b * VAL + v];
            msk[idx] = m;
            if (m) s = -1e9f;
            vals[idx] = s;
            smax = fmaxf(smax, s);
        }
    }
    smax = fmaxf(smax, __shfl_xor(smax, 1));
    smax = fmaxf(smax, __shfl_xor(smax, 2));
    smax = fmaxf(smax, __shfl_xor(smax, 4));
    float sume = 0.f, cnt = 0.f;
    #pragma unroll
    for (int i = 0; i < 16; ++i) {
        vals[i] = __expf(vals[i] - smax);
        sume += vals[i];
        cnt  += msk[i] ? 0.f : 1.f;
    }
    sume += __shfl_xor(sume, 1);  cnt += __shfl_xor(cnt, 1);
    sume += __shfl_xor(sume, 2);  cnt += __shfl_xor(cnt, 2);
    sume += __shfl_xor(sume, 4);  cnt += __shfl_xor(cnt, 4);
    const float invse = 1.f / sume;
    const float invd  = 1.f / cnt;
    f16x8 wv0, wv1;
    #pragma unroll
    for (int i = 0; i < 8; ++i) {
        wv0[i] = (_Float16)(vals[i]     * invse);
        wv1[i] = (_Float16)(vals[i + 8] * invse);
    }
    *(f16x8*)&wLDS[r * WPAD + sl*16]     = wv0;
    *(f16x8*)&wLDS[r * WPAD + sl*16 + 8] = wv1;
    // mean: 64 e per thread, coalesced 256B/row-group
    const float* mrow = msum + (size_t)bq * DD;
    #pragma unroll
    for (int i = 0; i < 8; ++i) {
        int e = i*64 + sl*8;
        f32x4 m0 = *(const f32x4*)(mrow + e);
        f32x4 m1 = *(const f32x4*)(mrow + e + 4);
        f16x8 mh;
        #pragma unroll
        for (int c = 0; c < 4; ++c) {
            mh[c]     = (_Float16)(m0[c] * invd);
            mh[c + 4] = (_Float16)(m1[c] * invd);
        }
        *(f16x8*)&meanLDS[r * MPAD + e] = mh;
    }
    __syncthreads();

    // ---- phase B: gate GEMM (K=512, 4 chunks of 128) ----
    f32x4 accg = (f32x4){0.f, 0.f, 0.f, 0.f};
    const int a_off = (wm*16 + lr) * MPAD + quad*8;
    const int b_off = (wn*16 + lr) * WPAD + quad*8;
    const int st_off = r * WPAD + sl*16;
    #pragma unroll
    for (int cc = 0; cc < 4; ++cc) {
        const _Float16* wrow = WseT + (size_t)(d0 + r) * DD + cc*128 + sl*16;
        f16x8 bw0 = *(const f16x8*)(wrow);
        f16x8 bw1 = *(const f16x8*)(wrow + 8);
        *(f16x8*)&BLDS[st_off]     = bw0;
        *(f16x8*)&BLDS[st_off + 8] = bw1;
        __syncthreads();
        #pragma unroll
        for (int ks = 0; ks < 4; ++ks) {
            f16x8 fa = *(const f16x8*)&meanLDS[a_off + cc*128 + ks*32];
            f16x8 fb = *(const f16x8*)&BLDS[b_off + ks*32];
            accg = __builtin_amdgcn_mfma_f32_16x16x32_f16(fa, fb, accg, 0, 0, 0);
        }
        __syncthreads();
    }

    // ---- phase C: out GEMM (K=128) ----
    {
        const _Float16* vrow = vsT + ((size_t)b * DD + d0 + r) * VAL + sl*16;
        f16x8 bv0 = *(const f16x8*)(vrow);
        f16x8 bv1 = *(const f16x8*)(vrow + 8);
        *(f16x8*)&BLDS[st_off]     = bv0;
        *(f16x8*)&BLDS[st_off + 8] = bv1;
    }
    __syncthreads();
    f32x4 acco = (f32x4){0.f, 0.f, 0.f, 0.f};
    const int w_off = (wm*16 + lr) * WPAD + quad*8;
    #pragma unroll
    for (int ks = 0; ks < 4; ++ks) {
        f16x8 fa = *(const f16x8*)&wLDS[w_off + ks*32];
        f16x8 fb = *(const f16x8*)&BLDS[b_off + ks*32];
        acco = __builtin_amdgcn_mfma_f32_16x16x32_f16(fa, fb, acco, 0, 0, 0);
    }

    // ---- phase D: epilogue. C/D: col=lr (d), row=quad*4+reg (q) ----
    const int d = d0 + wn*16 + lr;
    const float bsev = bse[d];
    #pragma unroll
    for (int reg = 0; reg < 4; ++reg) {
        int q = q0 + wm*16 + quad*4 + reg;
        float g = fmaxf(accg[reg] + bsev, 0.f);
        g = 1.f / (1.f + __expf(-g));
        out[(size_t)q * DD + d] = g * acco[reg];
    }
}

extern "C" void kernel_launch(void* const* d_in, const int* in_sizes, int n_in,
                              void* d_out, int out_size, void* d_ws, size_t ws_size,
                              hipStream_t stream) {
    (void)in_sizes; (void)n_in; (void)out_size; (void)ws_size;
    const float* qs1 = (const float*)d_in[0];
    const float* ks  = (const float*)d_in[2];
    const float* vs  = (const float*)d_in[3];
    const int*   sg  = (const int*)d_in[4];
    const float* W1  = (const float*)d_in[5];
    const float* b1  = (const float*)d_in[6];
    const float* Wse = (const float*)d_in[7];
    const float* bse = (const float*)d_in[8];
    const float* W2  = (const float*)d_in[9];
    const float* b2  = (const float*)d_in[10];
    float* out = (float*)d_out;

    char* ws = (char*)d_ws;
    _Float16* W1T    = (_Float16*)(ws);                        // 512 KB
    _Float16* WseT   = (_Float16*)(ws + (512 << 10));          // 512 KB
    _Float16* vsT    = (_Float16*)(ws + (1 << 20));            // 512 KB
    float*    s_part = (float*)(ws + (1536 << 10));            // 1 MB  [BQ][4][VAL]
    float*    msum   = (float*)(ws + (2560 << 10));            // 1 MB
    _Float16* qH     = (_Float16*)(ws + (3584 << 10));         // 512 KB
    _Float16* ksH    = (_Float16*)(ws + (4096 << 10));         // 512 KB

    prep_kernel<<<dim3(16, 38), 256, 0, stream>>>(W1, W1T, Wse, WseT, vs, vsT,
                                                  qs1, qH, ks, ksH);
    gemm_h_kernel<<<dim3(BQ, 4), 256, 0, stream>>>(qH, ksH, sg, W1T, b1, W2, s_part, msum);
    final_kernel<<<dim3(16, 16), 256, 0, stream>>>(s_part, msum, sg, WseT, vsT, bse, b2, out);
}